// Round 20
// baseline (89.682 us; speedup 1.0000x reference)
//
#include <hip/hip_runtime.h>
#include <hip/hip_bf16.h>
#include <cstdint>

#define GN 4096      // N nodes
#define GIN 128      // IN_F
#define GF 64        // OUT_F
#define GH 8         // heads
#define GHF (GH*GF)  // 512
#define LOG2E 1.4426950408889634f

typedef _Float16 h8 __attribute__((ext_vector_type(8)));
typedef __fp16   g2 __attribute__((ext_vector_type(2)));   // cvt_pkrtz result type
typedef __attribute__((ext_vector_type(4))) float f32x4;

__device__ __forceinline__ float leaky(float t) { return fmaxf(t, 0.2f * t); }
// monotone float<->uint encoding for atomicMax on floats
__device__ __forceinline__ uint32_t fenc(float f) {
    uint32_t u = __float_as_uint(f);
    return (u & 0x80000000u) ? ~u : (u | 0x80000000u);
}
__device__ __forceinline__ float fdec(uint32_t k) {
    uint32_t u = (k & 0x80000000u) ? (k ^ 0x80000000u) : ~k;
    return __uint_as_float(u);
}
__device__ __forceinline__ h8 splat8(float x) {
    _Float16 v = (_Float16)x;
    h8 r = {v, v, v, v, v, v, v, v};
    return r;
}

// ---------------- Kernel 0: init mask flag + stmax slots ----------------
__global__ void gat_zeroflag(uint32_t* __restrict__ f, uint32_t* __restrict__ stmaxi) {
    if (blockIdx.x == 0 && threadIdx.x == 0) f[0] = 0u;
    if (blockIdx.x == 0 && threadIdx.x < GH) stmaxi[threadIdx.x] = 0u;
}

// ---------------- Kernel 1: fused projection + scores + stmax + fragconv(f16) + mask scan ----------------
__global__ __launch_bounds__(256) void gat_proj(const float* __restrict__ A,
                                                const float* __restrict__ W,
                                                const float* __restrict__ a_src,
                                                const float* __restrict__ a_tgt,
                                                const uint32_t* __restrict__ maskbits,
                                                float* __restrict__ ss,
                                                float* __restrict__ st,
                                                uint32_t* __restrict__ stmaxi,
                                                _Float16* __restrict__ bh,
                                                uint32_t* __restrict__ mflag) {
    __shared__ float lds[2 * 64 * 129];
    float* As = lds;               // [64][129]
    float* Ws = lds + 64 * 129;    // [64][129]
    const int n0 = blockIdx.x * 64;
    const int h  = blockIdx.y;
    const int j0 = h * 64;
    const int tid = threadIdx.x;
    const float4* A4 = (const float4*)A;
    const float4* W4 = (const float4*)W;
#pragma unroll
    for (int i = 0; i < 8; ++i) {
        int idx = tid + i * 256;
        int r = idx >> 5, c4 = idx & 31;
        float4 v = A4[(size_t)(n0 + r) * 32 + c4];
        As[r * 129 + c4 * 4 + 0] = v.x; As[r * 129 + c4 * 4 + 1] = v.y;
        As[r * 129 + c4 * 4 + 2] = v.z; As[r * 129 + c4 * 4 + 3] = v.w;
        float4 w = W4[(size_t)(j0 + r) * 32 + c4];
        Ws[r * 129 + c4 * 4 + 0] = w.x; Ws[r * 129 + c4 * 4 + 1] = w.y;
        Ws[r * 129 + c4 * 4 + 2] = w.z; Ws[r * 129 + c4 * 4 + 3] = w.w;
    }
    __syncthreads();
    const int tx = tid & 15, ty = tid >> 4;
    float acc[4][4] = {};
    for (int k = 0; k < 128; ++k) {
        float a[4], b[4];
#pragma unroll
        for (int i = 0; i < 4; ++i) { a[i] = As[(ty * 4 + i) * 129 + k]; b[i] = Ws[(tx * 4 + i) * 129 + k]; }
#pragma unroll
        for (int i = 0; i < 4; ++i)
#pragma unroll
            for (int j = 0; j < 4; ++j) acc[i][j] = fmaf(a[i], b[j], acc[i][j]);
    }
    __syncthreads();                       // done with As/Ws contents
    float* X = lds;                        // stage X = [64][65] fp32 tile
#pragma unroll
    for (int i = 0; i < 4; ++i)
#pragma unroll
        for (int j = 0; j < 4; ++j)
            X[(ty * 4 + i) * 65 + tx * 4 + j] = acc[i][j];
    __syncthreads();

    const int lane = tid & 63, w = tid >> 6;
    float s1 = 0.f, s2 = 0.f;
#pragma unroll
    for (int k = 0; k < 16; ++k) {
        int f = w * 16 + k;
        float x = X[lane * 65 + f];
        s1 = fmaf(x, a_src[j0 + f], s1);
        s2 = fmaf(x, a_tgt[j0 + f], s2);
    }
    float* ps = lds + 64 * 129;            // reuse Ws region: [8][64]
    ps[w * 64 + lane] = s1;
    ps[(4 + w) * 64 + lane] = s2;
    __syncthreads();
    if (w == 0) {
        float ssv = ps[lane] + ps[64 + lane] + ps[128 + lane] + ps[192 + lane];
        float stv = ps[256 + lane] + ps[320 + lane] + ps[384 + lane] + ps[448 + lane];
        ss[h * GN + n0 + lane] = ssv;
        st[h * GN + n0 + lane] = stv;
        // wave max of stv -> one atomicMax per block
        float m = stv;
#pragma unroll
        for (int d = 1; d < 64; d <<= 1) m = fmaxf(m, __shfl_xor(m, d));
        if (lane == 0) atomicMax(&stmaxi[h], fenc(m));
    }

#pragma unroll
    for (int rep = 0; rep < 2; ++rep) {
        int fid = tid + rep * 256;
        int t_local = fid >> 8, cf = (fid >> 6) & 3, lf = fid & 63;
        int gg = lf >> 4, c = lf & 15;
        h8 vh;
#pragma unroll
        for (int jj = 0; jj < 8; ++jj)
            vh[jj] = (_Float16)X[(t_local * 32 + gg * 8 + jj) * 65 + cf * 16 + c];
        ((h8*)bh)[((size_t)(h * 128 + (n0 >> 5) + t_local) * 4 + cf) * 64 + lf] = vh;
    }

    // ---- fused mask zero-scan (exact OR over all mask bits, grid-strided) ----
    uint32_t accOr = 0;
    const uint4* m4 = (const uint4*)maskbits;
    const int nblocks = gridDim.x * gridDim.y;           // 512
    const int bid = blockIdx.y * gridDim.x + blockIdx.x;
    const int total = (GN * GN) / 4;                     // uint4 count
    for (int i = bid * 256 + tid; i < total; i += nblocks * 256) {
        uint4 v = m4[i];
        accOr |= v.x | v.y | v.z | v.w;
    }
#pragma unroll
    for (int d = 1; d < 64; d <<= 1) accOr |= (uint32_t)__shfl_xor((int)accOr, d);
    if ((tid & 63) == 0 && accOr) atomicOr(mflag, 1u);
}

// ---------------- Kernel 5a: FAST attention, f16 packed P-math, q64/wave, depth-1 ----------------
// P = max(e1'·EP', e2'·EN') in packed f16; all factors <=1 by smx-rescale (overflow-safe).
// f16 MFMA. NO asm; NO launch-bounds cap; depth-1 (r13 lesson). S=8 key-splits for 4 blk/CU.
__global__ __launch_bounds__(256) void gat_attn_fast(const _Float16* __restrict__ bh,
                                                     const float* __restrict__ ss,
                                                     const float* __restrict__ st,
                                                     const uint32_t* __restrict__ stmaxi,
                                                     const uint32_t* __restrict__ mflag,
                                                     float* __restrict__ acc_p,
                                                     float* __restrict__ l_p,
                                                     int S) {
    if (mflag[0] != 0u) return;              // mask nonzero -> handled by gat_attn_mask
    const int lane = threadIdx.x & 63;
    const int h = blockIdx.y;                                  // same head for all 4 waves
    const int q0 = blockIdx.x * 256 + (threadIdx.x >> 6) * 64; // per-wave q-tile
    const int s = blockIdx.z;
    const int TPS = 128 / S;                 // even for S in {1,2,4,8}
    const int g = lane >> 4;
    const int c = lane & 15;

    const float smx = fdec(stmaxi[h]);
    const float smxL = smx * LOG2E;
    h8 EPh[4], ENh[4];
#pragma unroll
    for (int qf = 0; qf < 4; ++qf) {
        float ssa = ss[h * GN + q0 + qf * 16 + c];
        float caL = leaky(ssa + smx) * LOG2E;      // fixed softmax bound (log2 domain)
        // rescaled so EP',EN' <= 1 and e1',e2' <= 1 (f16-safe products)
        EPh[qf] = splat8(__builtin_amdgcn_exp2f(fmaf(ssa, LOG2E, smxL - caL)));
        ENh[qf] = splat8(__builtin_amdgcn_exp2f(fmaf(0.2f * ssa, LOG2E, 0.2f * smxL - caL)));
    }

    const h8 ONES = splat8(1.0f);

    f32x4 acc[4][4];
    f32x4 accL[4];
#pragma unroll
    for (int qf = 0; qf < 4; ++qf) {
        accL[qf] = (f32x4){0.f, 0.f, 0.f, 0.f};
#pragma unroll
        for (int cf = 0; cf < 4; ++cf) acc[qf][cf] = (f32x4){0.f, 0.f, 0.f, 0.f};
    }

    const int t0 = s * TPS;
    const float4* stp = (const float4*)&st[h * GN + t0 * 32 + g * 8];
    const h8* bhp = (const h8*)bh + ((size_t)(h * 128 + t0) * 4) * 64 + lane;

    float4 sA[2]; h8 HA[4];
    float4 sB[2]; h8 HB[4];

#define LOADT(sv, Hv) do {                                      \
    sv[0] = stp[0]; sv[1] = stp[1]; stp += 8;                   \
    _Pragma("unroll")                                           \
    for (int i = 0; i < 4; ++i) Hv[i] = bhp[i * 64];            \
    bhp += 256; } while (0)

#define COMPUTET(sv, Hv) do {                                               \
    float stvL[8] = {fmaf(sv[0].x, LOG2E, -smxL), fmaf(sv[0].y, LOG2E, -smxL), \
                     fmaf(sv[0].z, LOG2E, -smxL), fmaf(sv[0].w, LOG2E, -smxL), \
                     fmaf(sv[1].x, LOG2E, -smxL), fmaf(sv[1].y, LOG2E, -smxL), \
                     fmaf(sv[1].z, LOG2E, -smxL), fmaf(sv[1].w, LOG2E, -smxL)}; \
    union { g2 p[4]; h8 v; } E1, E2;                                        \
    _Pragma("unroll")                                                       \
    for (int p2 = 0; p2 < 4; ++p2) {                                        \
        E1.p[p2] = __builtin_amdgcn_cvt_pkrtz(                              \
            __builtin_amdgcn_exp2f(stvL[2 * p2]),                           \
            __builtin_amdgcn_exp2f(stvL[2 * p2 + 1]));                      \
        E2.p[p2] = __builtin_amdgcn_cvt_pkrtz(                              \
            __builtin_amdgcn_exp2f(0.2f * stvL[2 * p2]),                    \
            __builtin_amdgcn_exp2f(0.2f * stvL[2 * p2 + 1]));               \
    }                                                                       \
    _Pragma("unroll")                                                       \
    for (int qf = 0; qf < 4; ++qf) {                                        \
        h8 P = __builtin_elementwise_max(E1.v * EPh[qf], E2.v * ENh[qf]);   \
        _Pragma("unroll")                                                   \
        for (int cf = 0; cf < 4; ++cf)                                      \
            acc[qf][cf] = __builtin_amdgcn_mfma_f32_16x16x32_f16(P, Hv[cf], acc[qf][cf], 0, 0, 0); \
        accL[qf] = __builtin_amdgcn_mfma_f32_16x16x32_f16(P, ONES, accL[qf], 0, 0, 0); \
    } } while (0)

    LOADT(sA, HA);                       // tile t0
    for (int t = 0; t + 2 < TPS; t += 2) {
        LOADT(sB, HB);                   // tile t+1 in flight during compute of t
        COMPUTET(sA, HA);
        LOADT(sA, HA);                   // tile t+2 in flight during compute of t+1
        COMPUTET(sB, HB);
    }
    LOADT(sB, HB);                       // last tile (no further prefetch)
    COMPUTET(sA, HA);
    COMPUTET(sB, HB);

#undef LOADT
#undef COMPUTET

    // row-sums from ones-MFMA: D[row = g*4+r] identical across cols; store once per row
    if (c == 0) {
#pragma unroll
        for (int qf = 0; qf < 4; ++qf)
#pragma unroll
            for (int r = 0; r < 4; ++r)
                l_p[(size_t)(s * GH + h) * GN + q0 + qf * 16 + g * 4 + r] = accL[qf][r];
    }
    // store acc: D layout col=c, row=g*4+r
#pragma unroll
    for (int qf = 0; qf < 4; ++qf)
#pragma unroll
        for (int cf = 0; cf < 4; ++cf)
#pragma unroll
            for (int r = 0; r < 4; ++r)
                acc_p[((size_t)(s * GH + h) * GN + q0 + qf * 16 + g * 4 + r) * GF + cf * 16 + c]
                    = acc[qf][cf][r];
}

// ---------------- Kernel 5b: MASK fallback attention (q16), f16 MFMA, guarded ----------------
__global__ __launch_bounds__(256) void gat_attn_mask(const _Float16* __restrict__ bh,
                                                     const float* __restrict__ ss,
                                                     const float* __restrict__ st,
                                                     const uint32_t* __restrict__ stmaxi,
                                                     const float* __restrict__ mask,
                                                     const uint32_t* __restrict__ mflag,
                                                     float* __restrict__ acc_p,
                                                     float* __restrict__ l_p,
                                                     int S) {
    if (mflag[0] == 0u) return;              // mask zero -> handled by gat_attn_fast
    const int lane = threadIdx.x & 63;
    const int h = blockIdx.y * 4 + (threadIdx.x >> 6);
    const int q0 = blockIdx.x * 16;
    const int s = blockIdx.z;
    const int TPS = 128 / S;
    const int g = lane >> 4;

    const int qa = q0 + (lane & 15);
    const float ssa = ss[h * GN + qa];
    const float smx = fdec(stmaxi[h]);
    const float caL = leaky(ssa + smx) * LOG2E;
    const float KaP = fmaf(ssa, LOG2E, -caL), KaN = fmaf(0.2f * ssa, LOG2E, -caL);

    const h8 ONES = splat8(1.0f);

    f32x4 acc[4];
#pragma unroll
    for (int cf = 0; cf < 4; ++cf) acc[cf] = (f32x4){0.f, 0.f, 0.f, 0.f};
    f32x4 accL = (f32x4){0.f, 0.f, 0.f, 0.f};

    const int t0 = s * TPS;
    const float4* stp = (const float4*)&st[h * GN + t0 * 32 + g * 8];
    const float4* mpa = (const float4*)&mask[(size_t)qa * GN + t0 * 32 + g * 8];
    const h8* bhp = (const h8*)bh + ((size_t)(h * 128 + t0) * 4) * 64 + lane;

    for (int t = 0; t < TPS; ++t) {
        float4 s0 = stp[0], s1 = stp[1]; stp += 8;
        float4 a0 = mpa[0], a1 = mpa[1]; mpa += 8;
        h8 H[4];
#pragma unroll
        for (int i = 0; i < 4; ++i) H[i] = bhp[i * 64];
        bhp += 256;
        float stv[8] = {s0.x, s0.y, s0.z, s0.w, s1.x, s1.y, s1.z, s1.w};
        float mav[8] = {a0.x, a0.y, a0.z, a0.w, a1.x, a1.y, a1.z, a1.w};
        float pa[8];
#pragma unroll
        for (int j = 0; j < 8; ++j) {
            float stvL = stv[j] * LOG2E;
            float ea = fmaxf(stvL + KaP, fmaf(stvL, 0.2f, KaN));
            ea = fmaf(mav[j], LOG2E, ea);
            pa[j] = __builtin_amdgcn_exp2f(ea);
        }
        union { g2 p[4]; h8 v; } P;
#pragma unroll
        for (int p2 = 0; p2 < 4; ++p2)
            P.p[p2] = __builtin_amdgcn_cvt_pkrtz(pa[2 * p2], pa[2 * p2 + 1]);
#pragma unroll
        for (int cf = 0; cf < 4; ++cf)
            acc[cf] = __builtin_amdgcn_mfma_f32_16x16x32_f16(P.v, H[cf], acc[cf], 0, 0, 0);
        accL = __builtin_amdgcn_mfma_f32_16x16x32_f16(P.v, ONES, accL, 0, 0, 0);
    }

    if ((lane & 15) == 0) {
#pragma unroll
        for (int r = 0; r < 4; ++r)
            l_p[(size_t)(s * GH + h) * GN + q0 + g * 4 + r] = accL[r];
    }
#pragma unroll
    for (int cf = 0; cf < 4; ++cf)
#pragma unroll
        for (int r = 0; r < 4; ++r)
            acc_p[((size_t)(s * GH + h) * GN + q0 + g * 4 + r) * GF + cf * 16 + (lane & 15)]
                = acc[cf][r];
}

// ---------------- Kernel 6: combine splits, head-mean, relu (float4) ----------------
__global__ __launch_bounds__(256) void gat_combine(const float* __restrict__ acc_p,
                                                   const float* __restrict__ l_p,
                                                   float* __restrict__ out, int S) {
    const int idx = blockIdx.x * 256 + threadIdx.x;    // n*16 + f4
    const int n = idx >> 4, f4 = idx & 15;
    const float4* ap = (const float4*)acc_p;
    float4 r = {0.f, 0.f, 0.f, 0.f};
#pragma unroll
    for (int h = 0; h < GH; ++h) {
        float4 a = {0.f, 0.f, 0.f, 0.f};
        float l = 0.f;
        for (int s = 0; s < S; ++s) {
            float4 v = ap[((size_t)(s * GH + h) * GN + n) * 16 + f4];
            a.x += v.x; a.y += v.y; a.z += v.z; a.w += v.w;
            l += l_p[(size_t)(s * GH + h) * GN + n];
        }
        float il = 1.0f / l;
        r.x += a.x * il; r.y += a.y * il; r.z += a.z * il; r.w += a.w * il;
    }
    float4 o;
    o.x = fmaxf(r.x * 0.125f, 0.f);
    o.y = fmaxf(r.y * 0.125f, 0.f);
    o.z = fmaxf(r.z * 0.125f, 0.f);
    o.w = fmaxf(r.w * 0.125f, 0.f);
    ((float4*)out)[idx] = o;
}

extern "C" void kernel_launch(void* const* d_in, const int* in_sizes, int n_in,
                              void* d_out, int out_size, void* d_ws, size_t ws_size,
                              hipStream_t stream) {
    const float* A     = (const float*)d_in[0];
    const float* mask  = (const float*)d_in[1];
    const float* Wp    = (const float*)d_in[2];
    const float* a_src = (const float*)d_in[3];
    const float* a_tgt = (const float*)d_in[4];
    float* out = (float*)d_out;

    char* w = (char*)d_ws;
    float* ss    = (float*)w;              w += (size_t)GH * GN * 4;
    float* st    = (float*)w;              w += (size_t)GH * GN * 4;
    uint32_t* stmaxi = (uint32_t*)w;       w += 256;
    uint32_t* mflag  = (uint32_t*)w;       w += 256;
    _Float16* bh = (_Float16*)w;           w += (size_t)GH * 128 * 4 * 64 * 8 * 2; // 4 MB
    size_t base = (size_t)(w - (char*)d_ws);
    size_t per_s = (size_t)GH * GN * GF * 4 + (size_t)GH * GN * 4;           // 8.5 MB
    int S = 8;                             // 1024 blocks -> 4 blk/CU (falls back if ws small)
    while (S > 1 && base + (size_t)S * per_s > ws_size) S >>= 1;
    float* acc_p = (float*)w;              w += (size_t)S * GH * GN * GF * 4;
    float* l_p   = (float*)w;

    gat_zeroflag<<<1, 64, 0, stream>>>(mflag, stmaxi);
    gat_proj<<<dim3(GN / 64, GH), 256, 0, stream>>>(A, Wp, a_src, a_tgt,
                                                    (const uint32_t*)mask,
                                                    ss, st, stmaxi, bh, mflag);
    gat_attn_fast<<<dim3(GN / 256, GH, S), 256, 0, stream>>>(bh, ss, st, stmaxi,
                                                             mflag, acc_p, l_p, S);
    gat_attn_mask<<<dim3(GN / 16, 2, S), 256, 0, stream>>>(bh, ss, st, stmaxi, mask,
                                                           mflag, acc_p, l_p, S);
    gat_combine<<<(GN * 16) / 256, 256, 0, stream>>>(acc_p, l_p, out, S);
}

// Round 21
// 78.285 us; speedup vs baseline: 1.1456x; 1.1456x over previous
//
#include <hip/hip_runtime.h>
#include <hip/hip_bf16.h>
#include <cstdint>

#define GN 4096      // N nodes
#define GIN 128      // IN_F
#define GF 64        // OUT_F
#define GH 8         // heads
#define GHF (GH*GF)  // 512
#define LOG2E 1.4426950408889634f

typedef _Float16 h8 __attribute__((ext_vector_type(8)));
typedef __fp16   g2 __attribute__((ext_vector_type(2)));   // cvt_pkrtz result type
typedef __attribute__((ext_vector_type(4))) float f32x4;

__device__ __forceinline__ float leaky(float t) { return fmaxf(t, 0.2f * t); }
// monotone float<->uint encoding for atomicMax on floats
__device__ __forceinline__ uint32_t fenc(float f) {
    uint32_t u = __float_as_uint(f);
    return (u & 0x80000000u) ? ~u : (u | 0x80000000u);
}
__device__ __forceinline__ float fdec(uint32_t k) {
    uint32_t u = (k & 0x80000000u) ? (k ^ 0x80000000u) : ~k;
    return __uint_as_float(u);
}
__device__ __forceinline__ h8 splat8(float x) {
    _Float16 v = (_Float16)x;
    h8 r = {v, v, v, v, v, v, v, v};
    return r;
}

// ---------------- Kernel 0: init mask flag + stmax slots ----------------
__global__ void gat_zeroflag(uint32_t* __restrict__ f, uint32_t* __restrict__ stmaxi) {
    if (blockIdx.x == 0 && threadIdx.x == 0) f[0] = 0u;
    if (blockIdx.x == 0 && threadIdx.x < GH) stmaxi[threadIdx.x] = 0u;
}

// ---------------- Kernel 1: fused projection + scores + stmax + fragconv(f16) + mask scan ----------------
__global__ __launch_bounds__(256) void gat_proj(const float* __restrict__ A,
                                                const float* __restrict__ W,
                                                const float* __restrict__ a_src,
                                                const float* __restrict__ a_tgt,
                                                const uint32_t* __restrict__ maskbits,
                                                float* __restrict__ ss,
                                                float* __restrict__ st,
                                                uint32_t* __restrict__ stmaxi,
                                                _Float16* __restrict__ bh,
                                                uint32_t* __restrict__ mflag) {
    __shared__ float lds[2 * 64 * 129];
    float* As = lds;               // [64][129]
    float* Ws = lds + 64 * 129;    // [64][129]
    const int n0 = blockIdx.x * 64;
    const int h  = blockIdx.y;
    const int j0 = h * 64;
    const int tid = threadIdx.x;
    const float4* A4 = (const float4*)A;
    const float4* W4 = (const float4*)W;
#pragma unroll
    for (int i = 0; i < 8; ++i) {
        int idx = tid + i * 256;
        int r = idx >> 5, c4 = idx & 31;
        float4 v = A4[(size_t)(n0 + r) * 32 + c4];
        As[r * 129 + c4 * 4 + 0] = v.x; As[r * 129 + c4 * 4 + 1] = v.y;
        As[r * 129 + c4 * 4 + 2] = v.z; As[r * 129 + c4 * 4 + 3] = v.w;
        float4 w = W4[(size_t)(j0 + r) * 32 + c4];
        Ws[r * 129 + c4 * 4 + 0] = w.x; Ws[r * 129 + c4 * 4 + 1] = w.y;
        Ws[r * 129 + c4 * 4 + 2] = w.z; Ws[r * 129 + c4 * 4 + 3] = w.w;
    }
    __syncthreads();
    const int tx = tid & 15, ty = tid >> 4;
    float acc[4][4] = {};
    for (int k = 0; k < 128; ++k) {
        float a[4], b[4];
#pragma unroll
        for (int i = 0; i < 4; ++i) { a[i] = As[(ty * 4 + i) * 129 + k]; b[i] = Ws[(tx * 4 + i) * 129 + k]; }
#pragma unroll
        for (int i = 0; i < 4; ++i)
#pragma unroll
            for (int j = 0; j < 4; ++j) acc[i][j] = fmaf(a[i], b[j], acc[i][j]);
    }
    __syncthreads();                       // done with As/Ws contents
    float* X = lds;                        // stage X = [64][65] fp32 tile
#pragma unroll
    for (int i = 0; i < 4; ++i)
#pragma unroll
        for (int j = 0; j < 4; ++j)
            X[(ty * 4 + i) * 65 + tx * 4 + j] = acc[i][j];
    __syncthreads();

    const int lane = tid & 63, w = tid >> 6;
    float s1 = 0.f, s2 = 0.f;
#pragma unroll
    for (int k = 0; k < 16; ++k) {
        int f = w * 16 + k;
        float x = X[lane * 65 + f];
        s1 = fmaf(x, a_src[j0 + f], s1);
        s2 = fmaf(x, a_tgt[j0 + f], s2);
    }
    float* ps = lds + 64 * 129;            // reuse Ws region: [8][64]
    ps[w * 64 + lane] = s1;
    ps[(4 + w) * 64 + lane] = s2;
    __syncthreads();
    if (w == 0) {
        float ssv = ps[lane] + ps[64 + lane] + ps[128 + lane] + ps[192 + lane];
        float stv = ps[256 + lane] + ps[320 + lane] + ps[384 + lane] + ps[448 + lane];
        ss[h * GN + n0 + lane] = ssv;
        st[h * GN + n0 + lane] = stv;
        // wave max of stv -> one atomicMax per block
        float m = stv;
#pragma unroll
        for (int d = 1; d < 64; d <<= 1) m = fmaxf(m, __shfl_xor(m, d));
        if (lane == 0) atomicMax(&stmaxi[h], fenc(m));
    }

#pragma unroll
    for (int rep = 0; rep < 2; ++rep) {
        int fid = tid + rep * 256;
        int t_local = fid >> 8, cf = (fid >> 6) & 3, lf = fid & 63;
        int gg = lf >> 4, c = lf & 15;
        h8 vh;
#pragma unroll
        for (int jj = 0; jj < 8; ++jj)
            vh[jj] = (_Float16)X[(t_local * 32 + gg * 8 + jj) * 65 + cf * 16 + c];
        ((h8*)bh)[((size_t)(h * 128 + (n0 >> 5) + t_local) * 4 + cf) * 64 + lf] = vh;
    }

    // ---- fused mask zero-scan (exact OR over all mask bits, grid-strided) ----
    uint32_t accOr = 0;
    const uint4* m4 = (const uint4*)maskbits;
    const int nblocks = gridDim.x * gridDim.y;           // 512
    const int bid = blockIdx.y * gridDim.x + blockIdx.x;
    const int total = (GN * GN) / 4;                     // uint4 count
    for (int i = bid * 256 + tid; i < total; i += nblocks * 256) {
        uint4 v = m4[i];
        accOr |= v.x | v.y | v.z | v.w;
    }
#pragma unroll
    for (int d = 1; d < 64; d <<= 1) accOr |= (uint32_t)__shfl_xor((int)accOr, d);
    if ((tid & 63) == 0 && accOr) atomicOr(mflag, 1u);
}

// ---------------- Kernel 5a: FAST attention, f16 packed P-math, q64/wave, depth-1 ----------------
// P = max(e1'·EP', e2'·EN') in packed f16; all factors <=1 by smx-rescale (overflow-safe).
// f16 MFMA. NO asm; NO launch-bounds cap; depth-1 (r13 lesson); S=4 (r20: S=8 regresses).
__global__ __launch_bounds__(256) void gat_attn_fast(const _Float16* __restrict__ bh,
                                                     const float* __restrict__ ss,
                                                     const float* __restrict__ st,
                                                     const uint32_t* __restrict__ stmaxi,
                                                     const uint32_t* __restrict__ mflag,
                                                     float* __restrict__ acc_p,
                                                     float* __restrict__ l_p,
                                                     int S) {
    if (mflag[0] != 0u) return;              // mask nonzero -> handled by gat_attn_mask
    const int lane = threadIdx.x & 63;
    const int h = blockIdx.y;                                  // same head for all 4 waves
    const int q0 = blockIdx.x * 256 + (threadIdx.x >> 6) * 64; // per-wave q-tile
    const int s = blockIdx.z;
    const int TPS = 128 / S;                 // even for S in {1,2,4}
    const int g = lane >> 4;
    const int c = lane & 15;

    const float smx = fdec(stmaxi[h]);
    const float smxL = smx * LOG2E;
    h8 EPh[4], ENh[4];
#pragma unroll
    for (int qf = 0; qf < 4; ++qf) {
        float ssa = ss[h * GN + q0 + qf * 16 + c];
        float caL = leaky(ssa + smx) * LOG2E;      // fixed softmax bound (log2 domain)
        // rescaled so EP',EN' <= 1 and e1',e2' <= 1 (f16-safe products)
        EPh[qf] = splat8(__builtin_amdgcn_exp2f(fmaf(ssa, LOG2E, smxL - caL)));
        ENh[qf] = splat8(__builtin_amdgcn_exp2f(fmaf(0.2f * ssa, LOG2E, 0.2f * smxL - caL)));
    }

    const h8 ONES = splat8(1.0f);

    f32x4 acc[4][4];
    f32x4 accL[4];
#pragma unroll
    for (int qf = 0; qf < 4; ++qf) {
        accL[qf] = (f32x4){0.f, 0.f, 0.f, 0.f};
#pragma unroll
        for (int cf = 0; cf < 4; ++cf) acc[qf][cf] = (f32x4){0.f, 0.f, 0.f, 0.f};
    }

    const int t0 = s * TPS;
    const float4* stp = (const float4*)&st[h * GN + t0 * 32 + g * 8];
    const h8* bhp = (const h8*)bh + ((size_t)(h * 128 + t0) * 4) * 64 + lane;

    float4 sA[2]; h8 HA[4];
    float4 sB[2]; h8 HB[4];

#define LOADT(sv, Hv) do {                                      \
    sv[0] = stp[0]; sv[1] = stp[1]; stp += 8;                   \
    _Pragma("unroll")                                           \
    for (int i = 0; i < 4; ++i) Hv[i] = bhp[i * 64];            \
    bhp += 256; } while (0)

#define COMPUTET(sv, Hv) do {                                               \
    float stvL[8] = {fmaf(sv[0].x, LOG2E, -smxL), fmaf(sv[0].y, LOG2E, -smxL), \
                     fmaf(sv[0].z, LOG2E, -smxL), fmaf(sv[0].w, LOG2E, -smxL), \
                     fmaf(sv[1].x, LOG2E, -smxL), fmaf(sv[1].y, LOG2E, -smxL), \
                     fmaf(sv[1].z, LOG2E, -smxL), fmaf(sv[1].w, LOG2E, -smxL)}; \
    union { g2 p[4]; h8 v; } E1, E2;                                        \
    _Pragma("unroll")                                                       \
    for (int p2 = 0; p2 < 4; ++p2) {                                        \
        E1.p[p2] = __builtin_amdgcn_cvt_pkrtz(                              \
            __builtin_amdgcn_exp2f(stvL[2 * p2]),                           \
            __builtin_amdgcn_exp2f(stvL[2 * p2 + 1]));                      \
        E2.p[p2] = __builtin_amdgcn_cvt_pkrtz(                              \
            __builtin_amdgcn_exp2f(0.2f * stvL[2 * p2]),                    \
            __builtin_amdgcn_exp2f(0.2f * stvL[2 * p2 + 1]));               \
    }                                                                       \
    _Pragma("unroll")                                                       \
    for (int qf = 0; qf < 4; ++qf) {                                        \
        h8 P = __builtin_elementwise_max(E1.v * EPh[qf], E2.v * ENh[qf]);   \
        _Pragma("unroll")                                                   \
        for (int cf = 0; cf < 4; ++cf)                                      \
            acc[qf][cf] = __builtin_amdgcn_mfma_f32_16x16x32_f16(P, Hv[cf], acc[qf][cf], 0, 0, 0); \
        accL[qf] = __builtin_amdgcn_mfma_f32_16x16x32_f16(P, ONES, accL[qf], 0, 0, 0); \
    } } while (0)

    LOADT(sA, HA);                       // tile t0
    for (int t = 0; t + 2 < TPS; t += 2) {
        LOADT(sB, HB);                   // tile t+1 in flight during compute of t
        COMPUTET(sA, HA);
        LOADT(sA, HA);                   // tile t+2 in flight during compute of t+1
        COMPUTET(sB, HB);
    }
    LOADT(sB, HB);                       // last tile (no further prefetch)
    COMPUTET(sA, HA);
    COMPUTET(sB, HB);

#undef LOADT
#undef COMPUTET

    // row-sums from ones-MFMA: D[row = g*4+r] identical across cols; store once per row
    if (c == 0) {
#pragma unroll
        for (int qf = 0; qf < 4; ++qf)
#pragma unroll
            for (int r = 0; r < 4; ++r)
                l_p[(size_t)(s * GH + h) * GN + q0 + qf * 16 + g * 4 + r] = accL[qf][r];
    }
    // store acc: D layout col=c, row=g*4+r
#pragma unroll
    for (int qf = 0; qf < 4; ++qf)
#pragma unroll
        for (int cf = 0; cf < 4; ++cf)
#pragma unroll
            for (int r = 0; r < 4; ++r)
                acc_p[((size_t)(s * GH + h) * GN + q0 + qf * 16 + g * 4 + r) * GF + cf * 16 + c]
                    = acc[qf][cf][r];
}

// ---------------- Kernel 5b: MASK fallback attention (q16), f16 MFMA, guarded ----------------
__global__ __launch_bounds__(256) void gat_attn_mask(const _Float16* __restrict__ bh,
                                                     const float* __restrict__ ss,
                                                     const float* __restrict__ st,
                                                     const uint32_t* __restrict__ stmaxi,
                                                     const float* __restrict__ mask,
                                                     const uint32_t* __restrict__ mflag,
                                                     float* __restrict__ acc_p,
                                                     float* __restrict__ l_p,
                                                     int S) {
    if (mflag[0] == 0u) return;              // mask zero -> handled by gat_attn_fast
    const int lane = threadIdx.x & 63;
    const int h = blockIdx.y * 4 + (threadIdx.x >> 6);
    const int q0 = blockIdx.x * 16;
    const int s = blockIdx.z;
    const int TPS = 128 / S;
    const int g = lane >> 4;

    const int qa = q0 + (lane & 15);
    const float ssa = ss[h * GN + qa];
    const float smx = fdec(stmaxi[h]);
    const float caL = leaky(ssa + smx) * LOG2E;
    const float KaP = fmaf(ssa, LOG2E, -caL), KaN = fmaf(0.2f * ssa, LOG2E, -caL);

    const h8 ONES = splat8(1.0f);

    f32x4 acc[4];
#pragma unroll
    for (int cf = 0; cf < 4; ++cf) acc[cf] = (f32x4){0.f, 0.f, 0.f, 0.f};
    f32x4 accL = (f32x4){0.f, 0.f, 0.f, 0.f};

    const int t0 = s * TPS;
    const float4* stp = (const float4*)&st[h * GN + t0 * 32 + g * 8];
    const float4* mpa = (const float4*)&mask[(size_t)qa * GN + t0 * 32 + g * 8];
    const h8* bhp = (const h8*)bh + ((size_t)(h * 128 + t0) * 4) * 64 + lane;

    for (int t = 0; t < TPS; ++t) {
        float4 s0 = stp[0], s1 = stp[1]; stp += 8;
        float4 a0 = mpa[0], a1 = mpa[1]; mpa += 8;
        h8 H[4];
#pragma unroll
        for (int i = 0; i < 4; ++i) H[i] = bhp[i * 64];
        bhp += 256;
        float stv[8] = {s0.x, s0.y, s0.z, s0.w, s1.x, s1.y, s1.z, s1.w};
        float mav[8] = {a0.x, a0.y, a0.z, a0.w, a1.x, a1.y, a1.z, a1.w};
        float pa[8];
#pragma unroll
        for (int j = 0; j < 8; ++j) {
            float stvL = stv[j] * LOG2E;
            float ea = fmaxf(stvL + KaP, fmaf(stvL, 0.2f, KaN));
            ea = fmaf(mav[j], LOG2E, ea);
            pa[j] = __builtin_amdgcn_exp2f(ea);
        }
        union { g2 p[4]; h8 v; } P;
#pragma unroll
        for (int p2 = 0; p2 < 4; ++p2)
            P.p[p2] = __builtin_amdgcn_cvt_pkrtz(pa[2 * p2], pa[2 * p2 + 1]);
#pragma unroll
        for (int cf = 0; cf < 4; ++cf)
            acc[cf] = __builtin_amdgcn_mfma_f32_16x16x32_f16(P.v, H[cf], acc[cf], 0, 0, 0);
        accL = __builtin_amdgcn_mfma_f32_16x16x32_f16(P.v, ONES, accL, 0, 0, 0);
    }

    if ((lane & 15) == 0) {
#pragma unroll
        for (int r = 0; r < 4; ++r)
            l_p[(size_t)(s * GH + h) * GN + q0 + g * 4 + r] = accL[r];
    }
#pragma unroll
    for (int cf = 0; cf < 4; ++cf)
#pragma unroll
        for (int r = 0; r < 4; ++r)
            acc_p[((size_t)(s * GH + h) * GN + q0 + g * 4 + r) * GF + cf * 16 + (lane & 15)]
                = acc[cf][r];
}

// ---------------- Kernel 6: combine splits, head-mean, relu (float4) ----------------
__global__ __launch_bounds__(256) void gat_combine(const float* __restrict__ acc_p,
                                                   const float* __restrict__ l_p,
                                                   float* __restrict__ out, int S) {
    const int idx = blockIdx.x * 256 + threadIdx.x;    // n*16 + f4
    const int n = idx >> 4, f4 = idx & 15;
    const float4* ap = (const float4*)acc_p;
    float4 r = {0.f, 0.f, 0.f, 0.f};
#pragma unroll
    for (int h = 0; h < GH; ++h) {
        float4 a = {0.f, 0.f, 0.f, 0.f};
        float l = 0.f;
        for (int s = 0; s < S; ++s) {
            float4 v = ap[((size_t)(s * GH + h) * GN + n) * 16 + f4];
            a.x += v.x; a.y += v.y; a.z += v.z; a.w += v.w;
            l += l_p[(size_t)(s * GH + h) * GN + n];
        }
        float il = 1.0f / l;
        r.x += a.x * il; r.y += a.y * il; r.z += a.z * il; r.w += a.w * il;
    }
    float4 o;
    o.x = fmaxf(r.x * 0.125f, 0.f);
    o.y = fmaxf(r.y * 0.125f, 0.f);
    o.z = fmaxf(r.z * 0.125f, 0.f);
    o.w = fmaxf(r.w * 0.125f, 0.f);
    ((float4*)out)[idx] = o;
}

extern "C" void kernel_launch(void* const* d_in, const int* in_sizes, int n_in,
                              void* d_out, int out_size, void* d_ws, size_t ws_size,
                              hipStream_t stream) {
    const float* A     = (const float*)d_in[0];
    const float* mask  = (const float*)d_in[1];
    const float* Wp    = (const float*)d_in[2];
    const float* a_src = (const float*)d_in[3];
    const float* a_tgt = (const float*)d_in[4];
    float* out = (float*)d_out;

    char* w = (char*)d_ws;
    float* ss    = (float*)w;              w += (size_t)GH * GN * 4;
    float* st    = (float*)w;              w += (size_t)GH * GN * 4;
    uint32_t* stmaxi = (uint32_t*)w;       w += 256;
    uint32_t* mflag  = (uint32_t*)w;       w += 256;
    _Float16* bh = (_Float16*)w;           w += (size_t)GH * 128 * 4 * 64 * 8 * 2; // 4 MB
    size_t base = (size_t)(w - (char*)d_ws);
    size_t per_s = (size_t)GH * GN * GF * 4 + (size_t)GH * GN * 4;           // 8.5 MB
    int S = 4;                             // r20 A/B: S=8 regresses (combine traffic)
    while (S > 1 && base + (size_t)S * per_s > ws_size) S >>= 1;
    float* acc_p = (float*)w;              w += (size_t)S * GH * GN * GF * 4;
    float* l_p   = (float*)w;

    gat_zeroflag<<<1, 64, 0, stream>>>(mflag, stmaxi);
    gat_proj<<<dim3(GN / 64, GH), 256, 0, stream>>>(A, Wp, a_src, a_tgt,
                                                    (const uint32_t*)mask,
                                                    ss, st, stmaxi, bh, mflag);
    gat_attn_fast<<<dim3(GN / 256, GH, S), 256, 0, stream>>>(bh, ss, st, stmaxi,
                                                             mflag, acc_p, l_p, S);
    gat_attn_mask<<<dim3(GN / 16, 2, S), 256, 0, stream>>>(bh, ss, st, stmaxi, mask,
                                                           mflag, acc_p, l_p, S);
    gat_combine<<<(GN * 16) / 256, 256, 0, stream>>>(acc_p, l_p, out, S);
}